// Round 13
// baseline (64.674 us; speedup 1.0000x reference)
//
#include <hip/hip_runtime.h>

#define NPTS 4096
#define N0V  10242
#define EPSV 1e-5f
#define NBLK 128
#define SLOTS 16

typedef unsigned short ushortT;
typedef __attribute__((ext_vector_type(8))) short short8;
typedef __attribute__((ext_vector_type(4))) float f32x4;

__device__ __forceinline__ float fmul(float a,float b){return __fmul_rn(a,b);}
__device__ __forceinline__ float fadd(float a,float b){return __fadd_rn(a,b);}
__device__ __forceinline__ float fsub(float a,float b){return __fsub_rn(a,b);}

__device__ __forceinline__ ushortT f2bf(float x){
  unsigned u = __float_as_uint(x);
  u = (u + 0x7fffu + ((u>>16)&1u)) >> 16;
  return (ushortT)u;
}

struct Params {
  const float* orig; const float* proj; const float* vertex; const int* nidx;
  const float* W0; const float* W1; const float* W2;
  const float* b0; const float* g0; const float* be0;
  const float* b1; const float* g1; const float* be1;
  const float* b2; const float* g2; const float* be2;
  float* accg; int* cnt; float* out;
};

// MFMA pair for one wave: 2 row-tiles (rt0, rt0+2) x 1 col-tile
template<int NS, int WSTR>
__device__ __forceinline__ void layer_mm(const ushortT* xa, const ushortT* wt,
    const float* __restrict__ bias, int li, int hi, int rt0, int colg,
    f32x4& accA, f32x4& accB)
{
  accA = (f32x4){0.f,0.f,0.f,0.f};
  accB = (f32x4){0.f,0.f,0.f,0.f};
  const ushortT* wbp = wt + colg*WSTR + hi*8;
  const ushortT* xaA = xa + (rt0*16 + li)*168 + hi*8;
  const ushortT* xaB = xaA + 32*168;
  #pragma unroll
  for (int s=0;s<NS;s++){
    short8 bb = *(const short8*)(wbp + s*32);
    short8 a0 = *(const short8*)(xaA + s*32);
    short8 a1 = *(const short8*)(xaB + s*32);
    accA = __builtin_amdgcn_mfma_f32_16x16x32_bf16(a0, bb, accA, 0,0,0);
    accB = __builtin_amdgcn_mfma_f32_16x16x32_bf16(a1, bb, accB, 0,0,0);
  }
  float bo = bias[colg];
  #pragma unroll
  for (int r=0;r<4;r++){ accA[r]+=bo; accB[r]+=bo; }
}

// R10/R12-proven stats: per-wave atomicAdd into 16 slots -> relaxed counter barrier ->
// 16-slot relaxed atomic read-back. No fences (R9 showed agent fences catastrophically slow);
// 16 slots required (R11 showed 1-slot fails).
__device__ __forceinline__ void layer_stats(const f32x4& accA, const f32x4& accB,
    float* __restrict__ accL, int* __restrict__ cntp,
    const float* __restrict__ g, const float* __restrict__ be,
    float* red2, float* stS, float* stB, int t, int blk, int lane, int colg)
{
  float s1=0.f, s2=0.f;
  #pragma unroll
  for (int r=0;r<4;r++){
    s1 += accA[r] + accB[r];
    s2 = fmaf(accA[r],accA[r],fmaf(accB[r],accB[r],s2));
  }
  s1 += __shfl_xor(s1,16); s1 += __shfl_xor(s1,32);
  s2 += __shfl_xor(s2,16); s2 += __shfl_xor(s2,32);
  if (lane < 16){
    float* sl = accL + (blk & (SLOTS-1))*256;
    atomicAdd(&sl[colg], s1);
    atomicAdd(&sl[128 + colg], s2);
  }
  __syncthreads();   // vmcnt(0): this block's adds globally performed
  if (t == 0){
    __hip_atomic_fetch_add(cntp, 1, __ATOMIC_RELAXED, __HIP_MEMORY_SCOPE_AGENT);
    while (__hip_atomic_load(cntp, __ATOMIC_RELAXED, __HIP_MEMORY_SCOPE_AGENT) < NBLK)
      __builtin_amdgcn_s_sleep(1);
  }
  __syncthreads();
  if (t < 256){
    float v = 0.f;
    #pragma unroll
    for (int s=0;s<SLOTS;s++)
      v += __hip_atomic_load(&accL[s*256 + t], __ATOMIC_RELAXED, __HIP_MEMORY_SCOPE_AGENT);
    red2[t] = v;
  }
  __syncthreads();
  if (t < 128){
    float S = red2[t], Q = red2[128 + t];
    float mean = S * (1.0f/8192.0f);
    float var  = Q * (1.0f/8192.0f) - mean*mean;
    float inv  = 1.0f / __fsqrt_rn(var + EPSV);
    float sc = g[t]*inv;
    stS[t] = sc;
    stB[t] = be[t] - mean*sc;
  }
  __syncthreads();
}

__global__ __launch_bounds__(1024) void k_fused(Params p)
{
  extern __shared__ __align__(16) char lds[];
  ushortT* wt0 = (ushortT*)lds;               // [128][168] bf16 @ ushort idx 0
  ushortT* wt1 = (ushortT*)(lds + 43008);     // [128][136] bf16 @ ushort idx 21504
  ushortT* wt2 = (ushortT*)(lds + 77824);     // [128][136] bf16 @ ushort idx 38912
  ushortT* xa  = (ushortT*)(lds + 112640);    // [64][168]  bf16
  __shared__ float red2[256];
  __shared__ float stS[128];
  __shared__ float stB[128];

  const int t    = threadIdx.x;
  const int blk  = blockIdx.x;
  const int lane = t & 63;
  const int w    = t >> 6;           // wave 0..15
  const int b    = blk >> 6;
  const int n0   = (blk & 63) * 64;
  const int li   = lane & 15;
  const int hi   = lane >> 4;
  const int rt0  = w >> 3;           // 0..1 -> row tiles rt0, rt0+2
  const int colg = (w & 7)*16 + li;  // output channel

  // ---------- phase A: feat scan+gather for this block's 64 rows (4 rows/wave) ----------
  {
    const float* vertex = p.vertex;
    float v0x=vertex[0], v0y=vertex[1], v0z=vertex[2];
    float r  = __fsqrt_rn(fadd(fadd(fmul(v0x,v0x),fmul(v0y,v0y)),fmul(v0z,v0z)));
    float rr = fmul(r,r);
    int j0 = p.nidx[0];
    float ax=vertex[3*j0], ay=vertex[3*j0+1], az=vertex[3*j0+2];
    float dx=fsub(v0x,ax), dy=fsub(v0y,ay), dz=fsub(v0z,az);
    float t2 = fadd(fadd(fmul(dx,dx),fmul(dy,dy)),fmul(dz,dz));

    #pragma unroll
    for (int rr_i=0; rr_i<4; rr_i++){
      const int row = w*4 + rr_i;
      const int n = n0 + row;
      const float* ob = p.orig + (b*19)*NPTS + n;
      float x=ob[0], y=ob[NPTS], z=ob[2*NPTS];
      float nrm = __fsqrt_rn(fadd(fadd(fmul(x,x),fmul(y,y)),fmul(z,z)));
      float s = __fdiv_rn(r,nrm);
      float px=fmul(x,s), py=fmul(y,s), pz=fmul(z,s);

      int first=0, has=0;
      for (int c0=0; c0<N0V; c0+=256){
        int m0=min(c0+lane,N0V-1), m1=min(c0+lane+64,N0V-1),
            m2=min(c0+lane+128,N0V-1), m3=min(c0+lane+192,N0V-1);
        float a0x=vertex[3*m0],a0y=vertex[3*m0+1],a0z=vertex[3*m0+2];
        float a1x=vertex[3*m1],a1y=vertex[3*m1+1],a1z=vertex[3*m1+2];
        float a2x=vertex[3*m2],a2y=vertex[3*m2+1],a2z=vertex[3*m2+2];
        float a3x=vertex[3*m3],a3y=vertex[3*m3+1],a3z=vertex[3*m3+2];
        float v20=fadd(fadd(fmul(a0x,a0x),fmul(a0y,a0y)),fmul(a0z,a0z));
        float v21=fadd(fadd(fmul(a1x,a1x),fmul(a1y,a1y)),fmul(a1z,a1z));
        float v22=fadd(fadd(fmul(a2x,a2x),fmul(a2y,a2y)),fmul(a2z,a2z));
        float v23=fadd(fadd(fmul(a3x,a3x),fmul(a3y,a3y)),fmul(a3z,a3z));
        float d0=fadd(fadd(fmul(px,a0x),fmul(py,a0y)),fmul(pz,a0z));
        float d1=fadd(fadd(fmul(px,a1x),fmul(py,a1y)),fmul(pz,a1z));
        float d2=fadd(fadd(fmul(px,a2x),fmul(py,a2y)),fmul(pz,a2z));
        float d3=fadd(fadd(fmul(px,a3x),fmul(py,a3y)),fmul(pz,a3z));
        bool h0 = (c0+lane    <N0V) && (fsub(fadd(rr,v20),fmul(2.0f,d0)) <= t2);
        bool h1 = (c0+lane+64 <N0V) && (fsub(fadd(rr,v21),fmul(2.0f,d1)) <= t2);
        bool h2 = (c0+lane+128<N0V) && (fsub(fadd(rr,v22),fmul(2.0f,d2)) <= t2);
        bool h3 = (c0+lane+192<N0V) && (fsub(fadd(rr,v23),fmul(2.0f,d3)) <= t2);
        unsigned long long bal;
        if ((bal=__ballot(h0))){ first=c0     +__builtin_ctzll(bal); has=1; break; }
        if ((bal=__ballot(h1))){ first=c0+ 64+__builtin_ctzll(bal); has=1; break; }
        if ((bal=__ballot(h2))){ first=c0+128+__builtin_ctzll(bal); has=1; break; }
        if ((bal=__ballot(h3))){ first=c0+192+__builtin_ctzll(bal); has=1; break; }
      }

      ushortT* rowp = xa + row*168;
      const float* pb = p.proj + (long)b*128*N0V;
      #pragma unroll
      for (int k=0;k<3;k++){
        int idx = lane + k*64;
        if (idx < 168){
          float v;
          if (idx < 19)        v = p.orig[(b*19+idx)*NPTS + n];
          else if (idx < 147)  v = has ? pb[(long)(idx-19)*N0V + first] : 0.0f;
          else                 v = 0.0f;
          rowp[idx] = f2bf(v);
        }
      }
    }
  }

  // ---------- phase B: pack weights f32 global -> bf16 LDS (55 els/thread, L2-hot) ----------
  {
    ushortT* wl = (ushortT*)lds;
    for (int u = t; u < 56320; u += 1024){
      float v;
      if (u < 21504){ int o=u/168, k=u-o*168; v = (k<147)? p.W0[o*147+k] : 0.f; }
      else if (u < 38912){ int q=u-21504; int o=q/136,k=q-o*136; v=(k<128)? p.W1[o*128+k]:0.f; }
      else { int q=u-38912; int o=q/136,k=q-o*136; v=(k<128)? p.W2[o*128+k]:0.f; }
      wl[u] = f2bf(v);
    }
  }
  __syncthreads();

  f32x4 accA, accB;

  // ---- layer 0: K=160 (5 MFMA steps), weights [128][168] ----
  layer_mm<5,168>(xa, wt0, p.b0, li, hi, rt0, colg, accA, accB);
  layer_stats(accA, accB, p.accg,        p.cnt,   p.g0, p.be0, red2, stS, stB, t, blk, lane, colg);
  {
    float ss = stS[colg], sb = stB[colg];
    #pragma unroll
    for (int r=0;r<4;r++){
      int rowA = rt0*16 + hi*4 + r;
      xa[rowA*168 + colg]      = f2bf(fmaxf(fmaf(accA[r], ss, sb), 0.f));
      xa[(rowA+32)*168 + colg] = f2bf(fmaxf(fmaf(accB[r], ss, sb), 0.f));
    }
  }
  __syncthreads();

  // ---- layer 1: K=128 (4 steps), weights [128][136] ----
  layer_mm<4,136>(xa, wt1, p.b1, li, hi, rt0, colg, accA, accB);
  layer_stats(accA, accB, p.accg + 4096, p.cnt+1, p.g1, p.be1, red2, stS, stB, t, blk, lane, colg);
  {
    float ss = stS[colg], sb = stB[colg];
    #pragma unroll
    for (int r=0;r<4;r++){
      int rowA = rt0*16 + hi*4 + r;
      xa[rowA*168 + colg]      = f2bf(fmaxf(fmaf(accA[r], ss, sb), 0.f));
      xa[(rowA+32)*168 + colg] = f2bf(fmaxf(fmaf(accB[r], ss, sb), 0.f));
    }
  }
  __syncthreads();

  // ---- layer 2: K=128 (4 steps), weights [128][136] ----
  layer_mm<4,136>(xa, wt2, p.b2, li, hi, rt0, colg, accA, accB);
  layer_stats(accA, accB, p.accg + 8192, p.cnt+2, p.g2, p.be2, red2, stS, stB, t, blk, lane, colg);
  {
    // final affine+relu -> f32 tile in dead wt0 region [64][132]
    float* ft = (float*)lds;
    float ss = stS[colg], sb = stB[colg];
    #pragma unroll
    for (int r=0;r<4;r++){
      int rowA = rt0*16 + hi*4 + r;
      ft[rowA*132 + colg]      = fmaxf(fmaf(accA[r], ss, sb), 0.f);
      ft[(rowA+32)*132 + colg] = fmaxf(fmaf(accB[r], ss, sb), 0.f);
    }
  }
  __syncthreads();
  {
    const float* ft = (const float*)lds;
    float* ob = p.out + (long)b*128*NPTS + n0;
    #pragma unroll
    for (int it=0; it<2; it++){
      int idx = t + it*1024;
      int oo = idx >> 4, jj = (idx & 15) * 4;
      float4 v;
      v.x = ft[(jj  )*132 + oo];
      v.y = ft[(jj+1)*132 + oo];
      v.z = ft[(jj+2)*132 + oo];
      v.w = ft[(jj+3)*132 + oo];
      *(float4*)(ob + (long)oo*NPTS + jj) = v;
    }
  }
}

extern "C" void kernel_launch(void* const* d_in, const int* in_sizes, int n_in,
                              void* d_out, int out_size, void* d_ws, size_t ws_size,
                              hipStream_t stream)
{
  const float* orig   = (const float*)d_in[0];
  const float* proj   = (const float*)d_in[1];
  const float* vertex = (const float*)d_in[2];
  const int*   nidx   = (const int*)d_in[3];
  const float* W0 = (const float*)d_in[4];
  const float* b0 = (const float*)d_in[5];
  const float* g0 = (const float*)d_in[6];
  const float* be0= (const float*)d_in[7];
  const float* W1 = (const float*)d_in[8];
  const float* b1 = (const float*)d_in[9];
  const float* g1 = (const float*)d_in[10];
  const float* be1= (const float*)d_in[11];
  const float* W2 = (const float*)d_in[12];
  const float* b2 = (const float*)d_in[13];
  const float* g2 = (const float*)d_in[14];
  const float* be2= (const float*)d_in[15];
  float* out = (float*)d_out;

  float* accg = (float*)d_ws;                 // 3*16*256 = 12288 floats
  int*   cnt  = (int*)((float*)d_ws + 12288); // 4 ints

  // zero slots + counters (graph-capturable async memset; no extra kernel launch)
  hipMemsetAsync(d_ws, 0, 12288*4 + 16, stream);

  hipFuncSetAttribute((const void*)k_fused,
                      hipFuncAttributeMaxDynamicSharedMemorySize, 134144);

  Params p{orig, proj, vertex, nidx, W0, W1, W2,
           b0, g0, be0, b1, g1, be1, b2, g2, be2,
           accg, cnt, out};
  void* args[] = {(void*)&p};
  hipLaunchCooperativeKernel((const void*)k_fused, dim3(NBLK), dim3(1024), args, 134144, stream);
}

// Round 15
// 37.259 us; speedup vs baseline: 1.7358x; 1.7358x over previous
//
#include <hip/hip_runtime.h>

#define NPTS 4096
#define N0V  10242
#define EPSV 1e-5f
#define SLOTS 16

typedef unsigned short ushortT;
typedef __attribute__((ext_vector_type(8))) short short8;
typedef __attribute__((ext_vector_type(4))) float f32x4;

__device__ __forceinline__ float fmul(float a,float b){return __fmul_rn(a,b);}
__device__ __forceinline__ float fadd(float a,float b){return __fadd_rn(a,b);}
__device__ __forceinline__ float fsub(float a,float b){return __fsub_rn(a,b);}

__device__ __forceinline__ ushortT f2bf(float x){
  unsigned u = __float_as_uint(x);
  u = (u + 0x7fffu + ((u>>16)&1u)) >> 16;
  return (ushortT)u;
}

// ---- per-wave 16x16 MFMA tile: rows rt*16..+15, cols colg-tile, K = NS*32 ----
template<int NS>
__device__ __forceinline__ void tile_mm(const ushortT* xa, const ushortT* wt, int wstr,
    int li, int hi, int rt, int colg, f32x4& acc)
{
  acc = (f32x4){0.f,0.f,0.f,0.f};
  const ushortT* wbp = wt + colg*wstr + hi*8;
  const ushortT* xap = xa + (rt*16 + li)*168 + hi*8;
  #pragma unroll
  for (int s=0;s<NS;s++){
    short8 bb = *(const short8*)(wbp + s*32);
    short8 a0 = *(const short8*)(xap + s*32);
    acc = __builtin_amdgcn_mfma_f32_16x16x32_bf16(a0, bb, acc, 0,0,0);
  }
}

// ---- per-wave partial sums -> 16-slot atomicAdd (visibility via kernel boundary) ----
__device__ __forceinline__ void tile_partials(const f32x4& acc, float* __restrict__ slotL,
                                              int blk, int lane, int colg)
{
  float s1=0.f, s2=0.f;
  #pragma unroll
  for (int r=0;r<4;r++){ s1 += acc[r]; s2 = fmaf(acc[r],acc[r],s2); }
  s1 += __shfl_xor(s1,16); s1 += __shfl_xor(s1,32);
  s2 += __shfl_xor(s2,16); s2 += __shfl_xor(s2,32);
  if (lane < 16){
    float* sl = slotL + (blk & (SLOTS-1))*256;
    atomicAdd(&sl[colg], s1);
    atomicAdd(&sl[128 + colg], s2);
  }
}

// ---- stats from previous kernel's slots: PLAIN loads (inter-dispatch barrier = sync) ----
__device__ __forceinline__ void slot_stats(const float* __restrict__ slotL,
    const float* __restrict__ g, const float* __restrict__ be,
    float* red2, float* stS, float* stB, int t)
{
  if (t < 256){
    float v = 0.f;
    #pragma unroll
    for (int s=0;s<SLOTS;s++) v += slotL[s*256 + t];
    red2[t] = v;
  }
  __syncthreads();
  if (t < 128){
    float S = red2[t], Q = red2[128 + t];
    float mean = S * (1.0f/8192.0f);
    float var  = Q * (1.0f/8192.0f) - mean*mean;
    float inv  = 1.0f / __fsqrt_rn(var + EPSV);
    float sc = g[t]*inv;
    stS[t] = sc;
    stB[t] = be[t] - mean*sc;
  }
  __syncthreads();
}

// ================= k_l0: scan own 32 rows + pack wt0 + L0 MFMA + partials + y0 =================
__global__ __launch_bounds__(1024) void k_l0(
    const float* __restrict__ orig, const float* __restrict__ proj,
    const float* __restrict__ vertex, const int* __restrict__ nidx,
    const float* __restrict__ W0, const float* __restrict__ b0,
    float* __restrict__ slot0, float* __restrict__ y0)
{
  __shared__ __align__(16) ushortT wt[128*168];   // 43008B
  __shared__ __align__(16) ushortT xa[32*168];    // 10752B

  const int t    = threadIdx.x;
  const int blk  = blockIdx.x;
  const int lane = t & 63;
  const int w    = t >> 6;          // wave 0..15
  const int b    = blk >> 7;
  const int n0   = (blk & 127) * 32;
  const int li   = lane & 15;
  const int hi   = lane >> 4;
  const int rt   = w >> 3;          // 0..1
  const int colg = (w & 7)*16 + li;

  // pack wt0 f32->bf16 (L2-hot broadcast reads)
  for (int u = t; u < 21504; u += 1024){
    int o = u/168, k = u - o*168;
    wt[u] = f2bf((k < 147) ? W0[o*147 + k] : 0.f);
  }

  // scan + gather: 2 rows per wave (R12-prep-verbatim math)
  {
    float v0x=vertex[0], v0y=vertex[1], v0z=vertex[2];
    float r  = __fsqrt_rn(fadd(fadd(fmul(v0x,v0x),fmul(v0y,v0y)),fmul(v0z,v0z)));
    float rr = fmul(r,r);
    int j0 = nidx[0];
    float ax=vertex[3*j0], ay=vertex[3*j0+1], az=vertex[3*j0+2];
    float dx=fsub(v0x,ax), dy=fsub(v0y,ay), dz=fsub(v0z,az);
    float t2 = fadd(fadd(fmul(dx,dx),fmul(dy,dy)),fmul(dz,dz));

    #pragma unroll
    for (int rr_i=0; rr_i<2; rr_i++){
      const int row = w*2 + rr_i;
      const int n = n0 + row;
      const float* ob = orig + (b*19)*NPTS + n;
      float x=ob[0], y=ob[NPTS], z=ob[2*NPTS];
      float nrm = __fsqrt_rn(fadd(fadd(fmul(x,x),fmul(y,y)),fmul(z,z)));
      float s = __fdiv_rn(r,nrm);
      float px=fmul(x,s), py=fmul(y,s), pz=fmul(z,s);

      int first=0, has=0;
      for (int c0=0; c0<N0V; c0+=256){
        int m0=min(c0+lane,N0V-1), m1=min(c0+lane+64,N0V-1),
            m2=min(c0+lane+128,N0V-1), m3=min(c0+lane+192,N0V-1);
        float a0x=vertex[3*m0],a0y=vertex[3*m0+1],a0z=vertex[3*m0+2];
        float a1x=vertex[3*m1],a1y=vertex[3*m1+1],a1z=vertex[3*m1+2];
        float a2x=vertex[3*m2],a2y=vertex[3*m2+1],a2z=vertex[3*m2+2];
        float a3x=vertex[3*m3],a3y=vertex[3*m3+1],a3z=vertex[3*m3+2];
        float v20=fadd(fadd(fmul(a0x,a0x),fmul(a0y,a0y)),fmul(a0z,a0z));
        float v21=fadd(fadd(fmul(a1x,a1x),fmul(a1y,a1y)),fmul(a1z,a1z));
        float v22=fadd(fadd(fmul(a2x,a2x),fmul(a2y,a2y)),fmul(a2z,a2z));
        float v23=fadd(fadd(fmul(a3x,a3x),fmul(a3y,a3y)),fmul(a3z,a3z));
        float d0=fadd(fadd(fmul(px,a0x),fmul(py,a0y)),fmul(pz,a0z));
        float d1=fadd(fadd(fmul(px,a1x),fmul(py,a1y)),fmul(pz,a1z));
        float d2=fadd(fadd(fmul(px,a2x),fmul(py,a2y)),fmul(pz,a2z));
        float d3=fadd(fadd(fmul(px,a3x),fmul(py,a3y)),fmul(pz,a3z));
        bool h0 = (c0+lane    <N0V) && (fsub(fadd(rr,v20),fmul(2.0f,d0)) <= t2);
        bool h1 = (c0+lane+64 <N0V) && (fsub(fadd(rr,v21),fmul(2.0f,d1)) <= t2);
        bool h2 = (c0+lane+128<N0V) && (fsub(fadd(rr,v22),fmul(2.0f,d2)) <= t2);
        bool h3 = (c0+lane+192<N0V) && (fsub(fadd(rr,v23),fmul(2.0f,d3)) <= t2);
        unsigned long long bal;
        if ((bal=__ballot(h0))){ first=c0     +__builtin_ctzll(bal); has=1; break; }
        if ((bal=__ballot(h1))){ first=c0+ 64+__builtin_ctzll(bal); has=1; break; }
        if ((bal=__ballot(h2))){ first=c0+128+__builtin_ctzll(bal); has=1; break; }
        if ((bal=__ballot(h3))){ first=c0+192+__builtin_ctzll(bal); has=1; break; }
      }

      ushortT* rowp = xa + row*168;
      const float* pb = proj + (long)b*128*N0V;
      #pragma unroll
      for (int k=0;k<3;k++){
        int idx = lane + k*64;
        if (idx < 168){
          float v;
          if (idx < 19)        v = orig[(b*19+idx)*NPTS + n];
          else if (idx < 147)  v = has ? pb[(long)(idx-19)*N0V + first] : 0.0f;
          else                 v = 0.0f;
          rowp[idx] = f2bf(v);
        }
      }
    }
  }
  __syncthreads();

  f32x4 acc;
  tile_mm<5>(xa, wt, 168, li, hi, rt, colg, acc);
  float bo = b0[colg];
  #pragma unroll
  for (int r=0;r<4;r++) acc[r] += bo;
  tile_partials(acc, slot0, blk, lane, colg);
  // y0 store (pre-BN, f32): GLOBAL row = b*4096 + n0 + local row   [R14 bug: b*4096 missing]
  #pragma unroll
  for (int r=0;r<4;r++)
    y0[(long)(b*4096 + n0 + rt*16 + hi*4 + r)*128 + colg] = acc[r];
}

// ================= k_lmid: stats(prev slots) + affine/relu + MFMA + partials + y out ==========
__global__ __launch_bounds__(1024) void k_lmid(
    const float* __restrict__ yin, const float* __restrict__ slotPrev,
    const float* __restrict__ g, const float* __restrict__ be,
    const float* __restrict__ W, const float* __restrict__ bias,
    float* __restrict__ slotCur, float* __restrict__ yout)
{
  __shared__ __align__(16) ushortT wt[128*136];   // 34816B
  __shared__ __align__(16) ushortT xa[32*168];
  __shared__ float red2[256];
  __shared__ float stS[128];
  __shared__ float stB[128];

  const int t    = threadIdx.x;
  const int blk  = blockIdx.x;
  const int lane = t & 63;
  const int w    = t >> 6;
  const int n0   = blk * 32;        // global row base 0..8191
  const int li   = lane & 15;
  const int hi   = lane >> 4;
  const int rt   = w >> 3;
  const int colg = (w & 7)*16 + li;

  // pack weights
  for (int u = t; u < 17408; u += 1024){
    int o = u/136, k = u - o*136;
    wt[u] = f2bf((k < 128) ? W[o*128 + k] : 0.f);
  }
  slot_stats(slotPrev, g, be, red2, stS, stB, t);

  // load yin rows, affine+relu -> bf16 xa (stride 168; zero pad cols 128..167)
  for (int i = t; i < 32*168; i += 1024){
    int row = i/168, c = i - row*168;
    float v = 0.f;
    if (c < 128) v = fmaxf(fmaf(yin[(long)(n0+row)*128 + c], stS[c], stB[c]), 0.f);
    xa[i] = f2bf(v);
  }
  __syncthreads();

  f32x4 acc;
  tile_mm<4>(xa, wt, 136, li, hi, rt, colg, acc);
  float bo = bias[colg];
  #pragma unroll
  for (int r=0;r<4;r++) acc[r] += bo;
  tile_partials(acc, slotCur, blk, lane, colg);
  #pragma unroll
  for (int r=0;r<4;r++)
    yout[(long)(n0 + rt*16 + hi*4 + r)*128 + colg] = acc[r];
}

// ================= k_out: stats(L2 slots) + affine/relu + transpose + store ==================
__global__ __launch_bounds__(1024) void k_out(
    const float* __restrict__ yin, const float* __restrict__ slotPrev,
    const float* __restrict__ g, const float* __restrict__ be,
    float* __restrict__ out)
{
  __shared__ float ft[32*132];
  __shared__ float red2[256];
  __shared__ float stS[128];
  __shared__ float stB[128];

  const int t   = threadIdx.x;
  const int blk = blockIdx.x;
  const int b   = blk >> 7;
  const int n0  = (blk & 127) * 32;

  slot_stats(slotPrev, g, be, red2, stS, stB, t);

  for (int i = t; i < 32*128; i += 1024){
    int row = i >> 7, c = i & 127;
    ft[row*132 + c] = fmaxf(fmaf(yin[(long)(b*4096 + n0 + row)*128 + c], stS[c], stB[c]), 0.f);
  }
  __syncthreads();

  float* ob = out + (long)b*128*NPTS + n0;
  {
    int oo = t >> 3, jj = (t & 7) * 4;   // 1024 threads cover 128 ch x 32 rows as float4
    float4 v;
    v.x = ft[(jj  )*132 + oo];
    v.y = ft[(jj+1)*132 + oo];
    v.z = ft[(jj+2)*132 + oo];
    v.w = ft[(jj+3)*132 + oo];
    *(float4*)(ob + (long)oo*NPTS + jj) = v;
  }
}

extern "C" void kernel_launch(void* const* d_in, const int* in_sizes, int n_in,
                              void* d_out, int out_size, void* d_ws, size_t ws_size,
                              hipStream_t stream)
{
  const float* orig   = (const float*)d_in[0];
  const float* proj   = (const float*)d_in[1];
  const float* vertex = (const float*)d_in[2];
  const int*   nidx   = (const int*)d_in[3];
  const float* W0 = (const float*)d_in[4];
  const float* b0 = (const float*)d_in[5];
  const float* g0 = (const float*)d_in[6];
  const float* be0= (const float*)d_in[7];
  const float* W1 = (const float*)d_in[8];
  const float* b1 = (const float*)d_in[9];
  const float* g1 = (const float*)d_in[10];
  const float* be1= (const float*)d_in[11];
  const float* W2 = (const float*)d_in[12];
  const float* b2 = (const float*)d_in[13];
  const float* g2 = (const float*)d_in[14];
  const float* be2= (const float*)d_in[15];
  float* out = (float*)d_out;

  float* ws    = (float*)d_ws;
  float* slot0 = ws;               // 16*256
  float* slot1 = ws + 4096;
  float* slot2 = ws + 8192;
  float* yA    = ws + 12288;       // 8192*128 f32 = 4MB
  float* yB    = yA + 8192*128;

  hipMemsetAsync(d_ws, 0, 3*4096*sizeof(float), stream);

  k_l0  <<<256, 1024, 0, stream>>>(orig, proj, vertex, nidx, W0, b0, slot0, yA);
  k_lmid<<<256, 1024, 0, stream>>>(yA, slot0, g0, be0, W1, b1, slot1, yB);
  k_lmid<<<256, 1024, 0, stream>>>(yB, slot1, g1, be1, W2, b2, slot2, yA);
  k_out <<<256, 1024, 0, stream>>>(yA, slot2, g2, be2, out);
}

// Round 16
// 35.444 us; speedup vs baseline: 1.8247x; 1.0512x over previous
//
#include <hip/hip_runtime.h>

#define NPTS 4096
#define N0V  10242
#define EPSV 1e-5f
#define SLOTS 16

typedef unsigned short ushortT;
typedef __attribute__((ext_vector_type(8))) short short8;
typedef __attribute__((ext_vector_type(4))) float f32x4;

__device__ __forceinline__ float fmul(float a,float b){return __fmul_rn(a,b);}
__device__ __forceinline__ float fadd(float a,float b){return __fadd_rn(a,b);}
__device__ __forceinline__ float fsub(float a,float b){return __fsub_rn(a,b);}

__device__ __forceinline__ ushortT f2bf(float x){
  unsigned u = __float_as_uint(x);
  u = (u + 0x7fffu + ((u>>16)&1u)) >> 16;
  return (ushortT)u;
}
__device__ __forceinline__ float bf2f(ushortT u){
  return __uint_as_float(((unsigned)u) << 16);
}

// ---- per-wave 16x16 MFMA tile: rows rt*16..+15, cols colg-tile, K = NS*32 ----
template<int NS>
__device__ __forceinline__ void tile_mm(const ushortT* xa, const ushortT* wt, int wstr,
    int li, int hi, int rt, int colg, f32x4& acc)
{
  acc = (f32x4){0.f,0.f,0.f,0.f};
  const ushortT* wbp = wt + colg*wstr + hi*8;
  const ushortT* xap = xa + (rt*16 + li)*168 + hi*8;
  #pragma unroll
  for (int s=0;s<NS;s++){
    short8 bb = *(const short8*)(wbp + s*32);
    short8 a0 = *(const short8*)(xap + s*32);
    acc = __builtin_amdgcn_mfma_f32_16x16x32_bf16(a0, bb, acc, 0,0,0);
  }
}

// ---- per-wave partial sums -> 16-slot atomicAdd (visibility via kernel boundary) ----
__device__ __forceinline__ void tile_partials(const f32x4& acc, float* __restrict__ slotL,
                                              int blk, int lane, int colg)
{
  float s1=0.f, s2=0.f;
  #pragma unroll
  for (int r=0;r<4;r++){ s1 += acc[r]; s2 = fmaf(acc[r],acc[r],s2); }
  s1 += __shfl_xor(s1,16); s1 += __shfl_xor(s1,32);
  s2 += __shfl_xor(s2,16); s2 += __shfl_xor(s2,32);
  if (lane < 16){
    float* sl = slotL + (blk & (SLOTS-1))*256;
    atomicAdd(&sl[colg], s1);
    atomicAdd(&sl[128 + colg], s2);
  }
}

// ---- stats from previous kernel's slots: PLAIN loads (inter-dispatch barrier = sync) ----
__device__ __forceinline__ void slot_stats(const float* __restrict__ slotL,
    const float* __restrict__ g, const float* __restrict__ be,
    float* red2, float* stS, float* stB, int t)
{
  if (t < 256){
    float v = 0.f;
    #pragma unroll
    for (int s=0;s<SLOTS;s++) v += slotL[s*256 + t];
    red2[t] = v;
  }
  __syncthreads();
  if (t < 128){
    float S = red2[t], Q = red2[128 + t];
    float mean = S * (1.0f/8192.0f);
    float var  = Q * (1.0f/8192.0f) - mean*mean;
    float inv  = 1.0f / __fsqrt_rn(var + EPSV);
    float sc = g[t]*inv;
    stS[t] = sc;
    stB[t] = be[t] - mean*sc;
  }
  __syncthreads();
}

// ================= k_l0: scan own 32 rows + pack wt0 + L0 MFMA + partials + y0(bf16) ==========
__global__ __launch_bounds__(1024) void k_l0(
    const float* __restrict__ orig, const float* __restrict__ proj,
    const float* __restrict__ vertex, const int* __restrict__ nidx,
    const float* __restrict__ W0, const float* __restrict__ b0,
    float* __restrict__ slot0, float* __restrict__ slotZ,   // slotZ = slot1 (zero 8192 floats)
    ushortT* __restrict__ y0)
{
  __shared__ __align__(16) ushortT wt[128*168];   // 43008B
  __shared__ __align__(16) ushortT xa[32*168];    // 10752B

  const int t    = threadIdx.x;
  const int blk  = blockIdx.x;
  const int lane = t & 63;
  const int w    = t >> 6;          // wave 0..15
  const int b    = blk >> 7;
  const int n0   = (blk & 127) * 32;
  const int li   = lane & 15;
  const int hi   = lane >> 4;
  const int rt   = w >> 3;          // 0..1
  const int colg = (w & 7)*16 + li;

  // zero slot1+slot2 for the later kernels (safe: they add only after k_l0 completes)
  if (blk < 8) slotZ[blk*1024 + t] = 0.f;

  // pack wt0 f32->bf16 (L2-hot reads)
  for (int u = t; u < 21504; u += 1024){
    int o = u/168, k = u - o*168;
    wt[u] = f2bf((k < 147) ? W0[o*147 + k] : 0.f);
  }

  // scan + gather: 2 rows per wave (R12-prep-verbatim math)
  {
    float v0x=vertex[0], v0y=vertex[1], v0z=vertex[2];
    float r  = __fsqrt_rn(fadd(fadd(fmul(v0x,v0x),fmul(v0y,v0y)),fmul(v0z,v0z)));
    float rr = fmul(r,r);
    int j0 = nidx[0];
    float ax=vertex[3*j0], ay=vertex[3*j0+1], az=vertex[3*j0+2];
    float dx=fsub(v0x,ax), dy=fsub(v0y,ay), dz=fsub(v0z,az);
    float t2 = fadd(fadd(fmul(dx,dx),fmul(dy,dy)),fmul(dz,dz));

    #pragma unroll
    for (int rr_i=0; rr_i<2; rr_i++){
      const int row = w*2 + rr_i;
      const int n = n0 + row;
      const float* ob = orig + (b*19)*NPTS + n;
      float x=ob[0], y=ob[NPTS], z=ob[2*NPTS];
      float nrm = __fsqrt_rn(fadd(fadd(fmul(x,x),fmul(y,y)),fmul(z,z)));
      float s = __fdiv_rn(r,nrm);
      float px=fmul(x,s), py=fmul(y,s), pz=fmul(z,s);

      int first=0, has=0;
      for (int c0=0; c0<N0V; c0+=256){
        int m0=min(c0+lane,N0V-1), m1=min(c0+lane+64,N0V-1),
            m2=min(c0+lane+128,N0V-1), m3=min(c0+lane+192,N0V-1);
        float a0x=vertex[3*m0],a0y=vertex[3*m0+1],a0z=vertex[3*m0+2];
        float a1x=vertex[3*m1],a1y=vertex[3*m1+1],a1z=vertex[3*m1+2];
        float a2x=vertex[3*m2],a2y=vertex[3*m2+1],a2z=vertex[3*m2+2];
        float a3x=vertex[3*m3],a3y=vertex[3*m3+1],a3z=vertex[3*m3+2];
        float v20=fadd(fadd(fmul(a0x,a0x),fmul(a0y,a0y)),fmul(a0z,a0z));
        float v21=fadd(fadd(fmul(a1x,a1x),fmul(a1y,a1y)),fmul(a1z,a1z));
        float v22=fadd(fadd(fmul(a2x,a2x),fmul(a2y,a2y)),fmul(a2z,a2z));
        float v23=fadd(fadd(fmul(a3x,a3x),fmul(a3y,a3y)),fmul(a3z,a3z));
        float d0=fadd(fadd(fmul(px,a0x),fmul(py,a0y)),fmul(pz,a0z));
        float d1=fadd(fadd(fmul(px,a1x),fmul(py,a1y)),fmul(pz,a1z));
        float d2=fadd(fadd(fmul(px,a2x),fmul(py,a2y)),fmul(pz,a2z));
        float d3=fadd(fadd(fmul(px,a3x),fmul(py,a3y)),fmul(pz,a3z));
        bool h0 = (c0+lane    <N0V) && (fsub(fadd(rr,v20),fmul(2.0f,d0)) <= t2);
        bool h1 = (c0+lane+64 <N0V) && (fsub(fadd(rr,v21),fmul(2.0f,d1)) <= t2);
        bool h2 = (c0+lane+128<N0V) && (fsub(fadd(rr,v22),fmul(2.0f,d2)) <= t2);
        bool h3 = (c0+lane+192<N0V) && (fsub(fadd(rr,v23),fmul(2.0f,d3)) <= t2);
        unsigned long long bal;
        if ((bal=__ballot(h0))){ first=c0     +__builtin_ctzll(bal); has=1; break; }
        if ((bal=__ballot(h1))){ first=c0+ 64+__builtin_ctzll(bal); has=1; break; }
        if ((bal=__ballot(h2))){ first=c0+128+__builtin_ctzll(bal); has=1; break; }
        if ((bal=__ballot(h3))){ first=c0+192+__builtin_ctzll(bal); has=1; break; }
      }

      ushortT* rowp = xa + row*168;
      const float* pb = proj + (long)b*128*N0V;
      #pragma unroll
      for (int k=0;k<3;k++){
        int idx = lane + k*64;
        if (idx < 168){
          float v;
          if (idx < 19)        v = orig[(b*19+idx)*NPTS + n];
          else if (idx < 147)  v = has ? pb[(long)(idx-19)*N0V + first] : 0.0f;
          else                 v = 0.0f;
          rowp[idx] = f2bf(v);
        }
      }
    }
  }
  __syncthreads();

  f32x4 acc;
  tile_mm<5>(xa, wt, 168, li, hi, rt, colg, acc);
  float bo = b0[colg];
  #pragma unroll
  for (int r=0;r<4;r++) acc[r] += bo;
  tile_partials(acc, slot0, blk, lane, colg);
  // y0 store (pre-BN, bf16)
  #pragma unroll
  for (int r=0;r<4;r++)
    y0[(long)(b*4096 + n0 + rt*16 + hi*4 + r)*128 + colg] = f2bf(acc[r]);
}

// ================= k_lmid: stats(prev slots) + affine/relu + MFMA + partials + y out ==========
__global__ __launch_bounds__(1024) void k_lmid(
    const ushortT* __restrict__ yin, const float* __restrict__ slotPrev,
    const float* __restrict__ g, const float* __restrict__ be,
    const float* __restrict__ W, const float* __restrict__ bias,
    float* __restrict__ slotCur, ushortT* __restrict__ yout)
{
  __shared__ __align__(16) ushortT wt[128*136];   // 34816B
  __shared__ __align__(16) ushortT xa[32*168];
  __shared__ float red2[256];
  __shared__ float stS[128];
  __shared__ float stB[128];

  const int t    = threadIdx.x;
  const int blk  = blockIdx.x;
  const int lane = t & 63;
  const int w    = t >> 6;
  const int n0   = blk * 32;        // global row base 0..8191
  const int li   = lane & 15;
  const int hi   = lane >> 4;
  const int rt   = w >> 3;
  const int colg = (w & 7)*16 + li;

  // pack weights
  for (int u = t; u < 17408; u += 1024){
    int o = u/136, k = u - o*136;
    wt[u] = f2bf((k < 128) ? W[o*128 + k] : 0.f);
  }
  // zero xa pad cols 128..167 (32 rows x 40)
  for (int u = t; u < 1280; u += 1024){
    int row = u/40, c = 128 + (u - row*40);
    xa[row*168 + c] = 0;
  }
  slot_stats(slotPrev, g, be, red2, stS, stB, t);

  // load yin rows (bf16 short8), affine+relu -> bf16 xa
  if (t < 512){
    int row = t >> 4, c0 = (t & 15) * 8;
    short8 yv = *(const short8*)(yin + (long)(n0+row)*128 + c0);
    short8 xv;
    #pragma unroll
    for (int j=0;j<8;j++){
      float f = bf2f((ushortT)yv[j]);
      f = fmaxf(fmaf(f, stS[c0+j], stB[c0+j]), 0.f);
      xv[j] = (short)f2bf(f);
    }
    *(short8*)(xa + row*168 + c0) = xv;
  }
  __syncthreads();

  f32x4 acc;
  tile_mm<4>(xa, wt, 136, li, hi, rt, colg, acc);
  float bo = bias[colg];
  #pragma unroll
  for (int r=0;r<4;r++) acc[r] += bo;
  tile_partials(acc, slotCur, blk, lane, colg);
  #pragma unroll
  for (int r=0;r<4;r++)
    yout[(long)(n0 + rt*16 + hi*4 + r)*128 + colg] = f2bf(acc[r]);
}

// ================= k_out: stats(L2 slots) + affine/relu + transpose + store ==================
__global__ __launch_bounds__(1024) void k_out(
    const ushortT* __restrict__ yin, const float* __restrict__ slotPrev,
    const float* __restrict__ g, const float* __restrict__ be,
    float* __restrict__ out)
{
  __shared__ float ft[32*132];
  __shared__ float red2[256];
  __shared__ float stS[128];
  __shared__ float stB[128];

  const int t   = threadIdx.x;
  const int blk = blockIdx.x;
  const int b   = blk >> 7;
  const int n0  = (blk & 127) * 32;

  slot_stats(slotPrev, g, be, red2, stS, stB, t);

  if (t < 512){
    int row = t >> 4, c0 = (t & 15) * 8;
    short8 yv = *(const short8*)(yin + (long)(b*4096 + n0 + row)*128 + c0);
    #pragma unroll
    for (int j=0;j<8;j++)
      ft[row*132 + c0 + j] = fmaxf(fmaf(bf2f((ushortT)yv[j]), stS[c0+j], stB[c0+j]), 0.f);
  }
  __syncthreads();

  float* ob = out + (long)b*128*NPTS + n0;
  {
    int oo = t >> 3, jj = (t & 7) * 4;   // 1024 threads cover 128 ch x 32 rows as float4
    float4 v;
    v.x = ft[(jj  )*132 + oo];
    v.y = ft[(jj+1)*132 + oo];
    v.z = ft[(jj+2)*132 + oo];
    v.w = ft[(jj+3)*132 + oo];
    *(float4*)(ob + (long)oo*NPTS + jj) = v;
  }
}

extern "C" void kernel_launch(void* const* d_in, const int* in_sizes, int n_in,
                              void* d_out, int out_size, void* d_ws, size_t ws_size,
                              hipStream_t stream)
{
  const float* orig   = (const float*)d_in[0];
  const float* proj   = (const float*)d_in[1];
  const float* vertex = (const float*)d_in[2];
  const int*   nidx   = (const int*)d_in[3];
  const float* W0 = (const float*)d_in[4];
  const float* b0 = (const float*)d_in[5];
  const float* g0 = (const float*)d_in[6];
  const float* be0= (const float*)d_in[7];
  const float* W1 = (const float*)d_in[8];
  const float* b1 = (const float*)d_in[9];
  const float* g1 = (const float*)d_in[10];
  const float* be1= (const float*)d_in[11];
  const float* W2 = (const float*)d_in[12];
  const float* b2 = (const float*)d_in[13];
  const float* g2 = (const float*)d_in[14];
  const float* be2= (const float*)d_in[15];
  float* out = (float*)d_out;

  float*   ws    = (float*)d_ws;
  float*   slot0 = ws;               // 16*256
  float*   slot1 = ws + 4096;
  float*   slot2 = ws + 8192;
  ushortT* yA    = (ushortT*)(ws + 12288);   // 8192*128 bf16 = 2MB
  ushortT* yB    = yA + 8192*128;

  hipMemsetAsync(d_ws, 0, 4096*sizeof(float), stream);   // slot0 only; slot1/2 zeroed by k_l0

  k_l0  <<<256, 1024, 0, stream>>>(orig, proj, vertex, nidx, W0, b0, slot0, slot1, yA);
  k_lmid<<<256, 1024, 0, stream>>>(yA, slot0, g0, be0, W1, b1, slot1, yB);
  k_lmid<<<256, 1024, 0, stream>>>(yB, slot1, g1, be1, W2, b2, slot2, yA);
  k_out <<<256, 1024, 0, stream>>>(yA, slot2, g2, be2, out);
}